// Round 1
// baseline (827.807 us; speedup 1.0000x reference)
//
#include <hip/hip_runtime.h>
#include <stdint.h>

#define N_NODES 50000
#define M_PAD   50176   // 196*256
#define R_REL   8
#define E_EDGES 100000
#define D_IN    768
#define D_H     256
#define N_CAT   2304    // 9*256 : [self | rel0..rel7]
#define LN_EPS  1e-5f

#define TILES_M256 196
#define TILES_N256 9
#define T_TOT256   1764   // 196*9
#define NCHUNK  49        // ceil(50000/1024)
#define EP_STRIDE 68      // epilogue repack row stride (u16): bank-conflict-free
#define E_PAD_MAX 960000  // 800k edges + <=150k pad slots

typedef __attribute__((ext_vector_type(8))) __bf16        bf16x8;
typedef __attribute__((ext_vector_type(4))) float         f32x4;
typedef __attribute__((ext_vector_type(8))) unsigned short u16x8;
typedef __attribute__((ext_vector_type(4))) unsigned short u16x4;
typedef __attribute__((ext_vector_type(4))) int            i32x4;

__device__ __forceinline__ float bf2f(unsigned short u) {
  union { float f; uint32_t i; } c; c.i = ((uint32_t)u) << 16; return c.f;
}
__device__ __forceinline__ unsigned short f2bf(float f) {
  uint32_t x = __float_as_uint(f);
  uint32_t r = (x + 0x7fffu + ((x >> 16) & 1u)) >> 16;   // RNE
  return (unsigned short)r;
}

__device__ __forceinline__ void gload_lds16(const void* g, uint32_t lds_off) {
  __builtin_amdgcn_global_load_lds(
      (const __attribute__((address_space(1))) void*)(uintptr_t)g,
      (__attribute__((address_space(3))) void*)(uintptr_t)lds_off, 16, 0, 0);
}

// ---------------- CSR build (node-major, relations flattened) ----------------
__global__ void k_deg(const int* __restrict__ tgt, int* __restrict__ deg) {
  int e = blockIdx.x * 256 + threadIdx.x;
  if (e >= R_REL * E_EDGES) return;
  int r = e / E_EDGES;
  atomicAdd(&deg[r * N_NODES + tgt[e]], 1);
}

// per-node total degree, padded to multiple of 4
__global__ void k_ndeg(const int* __restrict__ deg, int* __restrict__ pdeg) {
  int t = blockIdx.x * 256 + threadIdx.x;
  if (t >= N_NODES) return;
  int s = 0;
#pragma unroll
  for (int r = 0; r < R_REL; ++r) s += deg[r * N_NODES + t];
  pdeg[t] = (s + 3) & ~3;
}

__global__ __launch_bounds__(256)
void k_scan1(const int* __restrict__ deg, int* __restrict__ rowptr,
             int* __restrict__ bsum) {
  __shared__ int wtot[4];
  const int chunk = blockIdx.x, tid = threadIdx.x;
  const int wave = tid >> 6, lane = tid & 63;
  const int i0 = chunk * 1024 + tid * 4;
  int v0 = 0, v1 = 0, v2 = 0, v3 = 0;
  const int* d = deg;
  if (chunk != NCHUNK - 1) {
    i32x4 v = *(const i32x4*)(d + i0);
    v0 = v[0]; v1 = v[1]; v2 = v[2]; v3 = v[3];
  } else {
    if (i0 + 0 < N_NODES) v0 = d[i0 + 0];
    if (i0 + 1 < N_NODES) v1 = d[i0 + 1];
    if (i0 + 2 < N_NODES) v2 = d[i0 + 2];
    if (i0 + 3 < N_NODES) v3 = d[i0 + 3];
  }
  const int tsum = v0 + v1 + v2 + v3;
  int inc = tsum;
#pragma unroll
  for (int off = 1; off < 64; off <<= 1) {
    int t = __shfl_up(inc, off, 64);
    if (lane >= off) inc += t;
  }
  if (lane == 63) wtot[wave] = inc;
  __syncthreads();
  int woff = 0;
#pragma unroll
  for (int w = 0; w < 4; ++w) woff += (w < wave) ? wtot[w] : 0;
  int excl = woff + inc - tsum;
  int* rp = rowptr;
  if (i0 + 0 < N_NODES) rp[i0 + 0] = excl;
  if (i0 + 1 < N_NODES) rp[i0 + 1] = excl + v0;
  if (i0 + 2 < N_NODES) rp[i0 + 2] = excl + v0 + v1;
  if (i0 + 3 < N_NODES) rp[i0 + 3] = excl + v0 + v1 + v2;
  if (tid == 0) bsum[chunk] = wtot[0] + wtot[1] + wtot[2] + wtot[3];
}

__global__ __launch_bounds__(64)
void k_scan2(const int* __restrict__ bsum, int* __restrict__ chunkoff,
             int* __restrict__ rowptr) {
  const int lane = threadIdx.x & 63;
  int v = (lane < NCHUNK) ? bsum[lane] : 0;
  int inc = v;
#pragma unroll
  for (int off = 1; off < 64; off <<= 1) {
    int t = __shfl_up(inc, off, 64);
    if (lane >= off) inc += t;
  }
  if (lane < NCHUNK) chunkoff[lane] = inc - v;   // exclusive
  if (lane == NCHUNK - 1) rowptr[N_NODES] = inc;
}

__global__ __launch_bounds__(256)
void k_scan3(const int* __restrict__ chunkoff, int* __restrict__ rowptr) {
  const int chunk = blockIdx.x;
  if (chunk == 0) return;
  const int off = chunkoff[chunk];
  const int i0 = chunk * 1024 + threadIdx.x * 4;
#pragma unroll
  for (int j = 0; j < 4; ++j)
    if (i0 + j < N_NODES) rowptr[i0 + j] += off;
}

// per-node {start, padded_count}
__global__ void k_prep(const int* __restrict__ nodeptr, int2* __restrict__ scN) {
  int t = blockIdx.x * 256 + threadIdx.x;
  if (t >= N_NODES) return;
  scN[t] = make_int2(nodeptr[t], nodeptr[t + 1] - nodeptr[t]);
}

// fill flattened adjacency: e2[slot] = {src | rel<<16, nw[src]/deg[rel][tgt]}
__global__ void k_fill(const int* __restrict__ src, const int* __restrict__ tgt,
                       const float* __restrict__ nw, const int* __restrict__ nodeptr,
                       const int* __restrict__ deg, int* __restrict__ cursor,
                       int2* __restrict__ e2) {
  int e = blockIdx.x * 256 + threadIdx.x;
  if (e >= R_REL * E_EDGES) return;
  int r = e / E_EDGES;
  int t = tgt[e], s = src[e];
  int pos = atomicAdd(&cursor[t], 1);
  int slot = nodeptr[t] + pos;
  float w = nw[s] / (float)deg[r * N_NODES + t];
  e2[slot] = make_int2(s | (r << 16), __float_as_int(w));
}

// ---------------- conversions ----------------
__global__ void k_cvt_x(const float* __restrict__ x, unsigned short* __restrict__ xb) {
  const size_t i = ((size_t)blockIdx.x * 256 + threadIdx.x) * 4;
  if (i >= (size_t)N_NODES * D_IN) return;
  const f32x4 v = *(const f32x4*)(x + i);
  u16x4 o = { f2bf(v[0]), f2bf(v[1]), f2bf(v[2]), f2bf(v[3]) };
  *(u16x4*)(xb + i) = o;
}

// Wt[n][k] = n<256 ? Wself[k][n] : Wrel[(n-256)>>8][k][n&255]   (bf16, [N_CAT][K])
__global__ void k_cvt_w(const float* __restrict__ Ws, const float* __restrict__ Wr,
                        unsigned short* __restrict__ Wt, int K) {
  int idx = blockIdx.x * 256 + threadIdx.x;
  if (idx >= N_CAT * K) return;
  int n = idx / K, k = idx - n * K;
  float v = (n < 256) ? Ws[k * 256 + n]
                      : Wr[(size_t)((n - 256) >> 8) * K * 256 + k * 256 + (n & 255)];
  Wt[idx] = f2bf(v);
}

// ---------------- bf16 MFMA GEMM, 256x256 tile, BK=64, 8-phase counted-vmcnt ----------------
// C[M_PAD,N_CAT] = A @ Bt^T. 8 waves (2M x 4N), per-wave 128x64 output (acc[8][4]).
// LDS: bufA[2][256][64] @0, bufB[2][256][64] @65536 (128 KiB). Rows are 128 B =
// 8 x 16B chunks; chunk c of row r lives at slot c^(r&7) -> staging (linear dest,
// pre-swizzled global src) and fragment ds_read_b128 are both bank-conflict-free.
//
// Phase q (q=0..3) of K-tile t computes mi={2q,2q+1} x nj=0..3 x kk=0..1 (16 MFMA)
// and reads A rows {wm*128+32q..+31} -> A consumed front-to-back in 32-row strips.
// Staging schedule (legality: a region staged at phase p must be dead by end of
// phase p-1, enforced by the per-phase trailing barrier):
//   p0: t+1 A-halfY (rows 64-127,192-255) + t+1 B-half0   -> other buffer (dead)
//   p1: t+1 B-half1                                        -> other buffer (dead)
//   p2: t+2 A-halfX (rows 0-63,128-191)  -> SAME buffer, rows freed at p0/p1
// Boundary: s_waitcnt vmcnt(2) (only t+2 A-halfX in flight) + barrier. Never
// vmcnt(0) in steady state; drains to 0 only at the tail (t+2 >= nk).
__global__ __launch_bounds__(512, 2)
void k_gemm(const unsigned short* __restrict__ A, const unsigned short* __restrict__ Bt,
            unsigned short* __restrict__ C, int K) {
  __shared__ __align__(16) char smem[131072];

  // bijective XCD swizzle (nwg=1764, nwg%8=4) — m204 variant
  const int bid = blockIdx.x;
  const int xcd = bid & 7, idx = bid >> 3;
  const int q9 = T_TOT256 >> 3, rr = T_TOT256 & 7;       // 220, 4
  const int wg = (xcd < rr ? xcd * (q9 + 1)
                           : rr * (q9 + 1) + (xcd - rr) * q9) + idx;
  const int tm9 = wg / 9;
  const int tileM = tm9 * 256;
  const int tileN = (wg - tm9 * 9) * 256;

  const int tid  = threadIdx.x;
  const int wave = tid >> 6, lane = tid & 63;
  const int wmRow = (wave >> 2) * 128;                   // 2 M-waves
  const int wnRow = (wave & 3) * 64;                     // 4 N-waves
  const int c16 = lane & 15, fph = lane >> 4, x7 = lane & 7;

  // staging lanes: 512 threads cover one 64-row round (8 KiB) per gload
  const int srow = tid >> 3, sl8 = tid & 7;
  const int cch = sl8 ^ (srow & 7);                      // pre-swizzled global chunk
  const unsigned short* gA0 = A  + (size_t)(tileM + srow) * K + cch * 8;
  const unsigned short* gB0 = Bt + (size_t)(tileN + srow) * K + cch * 8;
  const uint32_t ldsA = (uint32_t)(uintptr_t)smem;
  const uint32_t ldsB = ldsA + 65536u;
  const uint32_t linA = (uint32_t)(srow * 128 + sl8 * 16);

#define STA(R0, tt) gload_lds16(gA0 + (size_t)(R0) * K + (size_t)(tt) * 64, \
                                ldsA + (uint32_t)(((tt) & 1) * 32768) + (uint32_t)((R0) * 128) + linA)
#define STB(R0, tt) gload_lds16(gB0 + (size_t)(R0) * K + (size_t)(tt) * 64, \
                                ldsB + (uint32_t)(((tt) & 1) * 32768) + (uint32_t)((R0) * 128) + linA)

  f32x4 acc[8][4] = {};

  // fragment read bases (row stride 128 B; chunk c of row r at slot c^(r&7), r&7==lane&7)
  const char* pA = smem          + (wmRow + c16) * 128;
  const char* pB = smem + 65536  + (wnRow + c16) * 128;

  const int nk = K >> 6;                                  // 12 (K=768) or 4 (K=256)

  // prologue: tile0 complete (8 loads) + tile1 A-halfX (2 loads)
  STA(0, 0); STA(128, 0); STA(64, 0); STA(192, 0);
  STB(0, 0); STB(64, 0);  STB(128, 0); STB(192, 0);
  STA(0, 1); STA(128, 1);
  asm volatile("s_waitcnt vmcnt(2)" ::: "memory");        // tile0 landed
  asm volatile("s_barrier" ::: "memory");

  for (int t = 0; t < nk; ++t) {
    const uint32_t bA = (uint32_t)(t & 1) * 32768u;
#pragma unroll
    for (int q = 0; q < 4; ++q) {
      bf16x8 af[2][2], bfr[2][4];
#pragma unroll
      for (int kk = 0; kk < 2; ++kk) {
        const int sA = ((kk * 4 + fph) ^ x7) * 16;
#pragma unroll
        for (int i2 = 0; i2 < 2; ++i2)
          af[i2][kk] = *(const bf16x8*)(pA + bA + (q * 2 + i2) * 2048 + sA);
#pragma unroll
        for (int nj = 0; nj < 4; ++nj)
          bfr[kk][nj] = *(const bf16x8*)(pB + bA + nj * 2048 + sA);
      }
      if (q == 0 && t + 1 < nk) { STA(64, t + 1); STA(192, t + 1); STB(0, t + 1); STB(64, t + 1); }
      if (q == 1 && t + 1 < nk) { STB(128, t + 1); STB(192, t + 1); }
      if (q == 2 && t + 2 < nk) { STA(0, t + 2); STA(128, t + 2); }
      asm volatile("s_barrier" ::: "memory");
      asm volatile("s_waitcnt lgkmcnt(0)" ::: "memory");
      __builtin_amdgcn_s_setprio(1);
#pragma unroll
      for (int i2 = 0; i2 < 2; ++i2)
#pragma unroll
        for (int nj = 0; nj < 4; ++nj)
#pragma unroll
          for (int kk = 0; kk < 2; ++kk)
            acc[q * 2 + i2][nj] = __builtin_amdgcn_mfma_f32_16x16x32_bf16(
                af[i2][kk], bfr[kk][nj], acc[q * 2 + i2][nj], 0, 0, 0);
      __builtin_amdgcn_s_setprio(0);
      if (q < 3) asm volatile("s_barrier" ::: "memory");
    }
    if (t + 1 < nk) {
      if (t + 2 < nk) asm volatile("s_waitcnt vmcnt(2)" ::: "memory");
      else            asm volatile("s_waitcnt vmcnt(0)" ::: "memory");
      asm volatile("s_barrier" ::: "memory");
    }
  }
  asm volatile("s_waitcnt vmcnt(0)" ::: "memory");        // free: already drained
  asm volatile("s_barrier" ::: "memory");                 // GEMM LDS dead -> reuse

#undef STA
#undef STB

  // epilogue: per-wave 128x64 output in two 64-row passes via LDS repack
  unsigned short* st = (unsigned short*)smem + wave * (64 * EP_STRIDE);
  const int rq4 = (lane >> 4) * 4, cq = lane & 15;
#pragma unroll
  for (int half = 0; half < 2; ++half) {
#pragma unroll
    for (int i = 0; i < 4; ++i)
#pragma unroll
      for (int j = 0; j < 4; ++j)
#pragma unroll
        for (int p = 0; p < 4; ++p)
          st[(i * 16 + rq4 + p) * EP_STRIDE + j * 16 + cq] = f2bf(acc[half * 4 + i][j][p]);
#pragma unroll
    for (int pass = 0; pass < 8; ++pass) {
      const int row = pass * 8 + (lane >> 3);
      const unsigned short* rp_ = st + row * EP_STRIDE + (lane & 7) * 8;
      u16x4 lo = *(const u16x4*)(rp_);
      u16x4 hi = *(const u16x4*)(rp_ + 4);
      u16x8 v = { lo[0], lo[1], lo[2], lo[3], hi[0], hi[1], hi[2], hi[3] };
      size_t off = (size_t)(tileM + wmRow + half * 64 + row) * N_CAT + tileN + wnRow + (lane & 7) * 8;
      *(u16x8*)(C + off) = v;
    }
  }
}

// ---------------- fused gather + mean + self + bias + ReLU + LayerNorm ----------------
// one wave per node, 4 channels/lane; single flattened edge loop, 4 edges in flight.
template <int FINAL>
__global__ __launch_bounds__(256)
void k_gather_ln(const unsigned short* __restrict__ Y, const int2* __restrict__ scN,
                 const int2* __restrict__ e2, const float* __restrict__ bias,
                 const float* __restrict__ g, const float* __restrict__ bln,
                 void* __restrict__ out) {
  const int wave = threadIdx.x >> 6, lane = threadIdx.x & 63;
  const int t = blockIdx.x * 4 + wave;
  if (t >= N_NODES) return;
  const int c0 = lane * 4;

  float a0, a1, a2, a3;
  {
    u16x4 sv = *(const u16x4*)(Y + (size_t)t * N_CAT + c0);
    f32x4 bb = *(const f32x4*)(bias + c0);
    a0 = bf2f(sv[0]) + bb[0];
    a1 = bf2f(sv[1]) + bb[1];
    a2 = bf2f(sv[2]) + bb[2];
    a3 = bf2f(sv[3]) + bb[3];
  }

  const int2 s = scN[t];                    // {start, padded_cnt (x4)}
  const int2* ep = e2 + s.x;
  for (int idx = 0; idx < s.y; idx += 4) {
    const int2 p0 = ep[idx + 0];
    const int2 p1 = ep[idx + 1];
    const int2 p2 = ep[idx + 2];
    const int2 p3 = ep[idx + 3];
    // addr: Y + src*2304 + (rel+1)*256 + c0 ; pad slots are {0,w=0} -> add 0
    const unsigned short* y0 = Y + (size_t)(p0.x & 0xFFFF) * N_CAT + (((p0.x >> 16) + 1) << 8) + c0;
    const unsigned short* y1 = Y + (size_t)(p1.x & 0xFFFF) * N_CAT + (((p1.x >> 16) + 1) << 8) + c0;
    const unsigned short* y2 = Y + (size_t)(p2.x & 0xFFFF) * N_CAT + (((p2.x >> 16) + 1) << 8) + c0;
    const unsigned short* y3 = Y + (size_t)(p3.x & 0xFFFF) * N_CAT + (((p3.x >> 16) + 1) << 8) + c0;
    u16x4 v0 = *(const u16x4*)y0;
    u16x4 v1 = *(const u16x4*)y1;
    u16x4 v2 = *(const u16x4*)y2;
    u16x4 v3 = *(const u16x4*)y3;
    const float w0 = __int_as_float(p0.y), w1 = __int_as_float(p1.y);
    const float w2 = __int_as_float(p2.y), w3 = __int_as_float(p3.y);
    a0 += w0 * bf2f(v0[0]) + w1 * bf2f(v1[0]) + w2 * bf2f(v2[0]) + w3 * bf2f(v3[0]);
    a1 += w0 * bf2f(v0[1]) + w1 * bf2f(v1[1]) + w2 * bf2f(v2[1]) + w3 * bf2f(v3[1]);
    a2 += w0 * bf2f(v0[2]) + w1 * bf2f(v1[2]) + w2 * bf2f(v2[2]) + w3 * bf2f(v3[2]);
    a3 += w0 * bf2f(v0[3]) + w1 * bf2f(v1[3]) + w2 * bf2f(v2[3]) + w3 * bf2f(v3[3]);
  }

  a0 = fmaxf(a0, 0.f); a1 = fmaxf(a1, 0.f); a2 = fmaxf(a2, 0.f); a3 = fmaxf(a3, 0.f);

  float s1 = (a0 + a1) + (a2 + a3);
#pragma unroll
  for (int off = 32; off > 0; off >>= 1) s1 += __shfl_xor(s1, off, 64);
  const float mu = s1 * (1.f / 256.f);
  const float d0 = a0 - mu, d1 = a1 - mu, d2 = a2 - mu, d3 = a3 - mu;
  float s2 = (d0 * d0 + d1 * d1) + (d2 * d2 + d3 * d3);
#pragma unroll
  for (int off = 32; off > 0; off >>= 1) s2 += __shfl_xor(s2, off, 64);
  const float rs = rsqrtf(s2 * (1.f / 256.f) + LN_EPS);

  f32x4 gg = *(const f32x4*)(g + c0);
  f32x4 ll = *(const f32x4*)(bln + c0);
  const float o0 = d0 * rs * gg[0] + ll[0];
  const float o1 = d1 * rs * gg[1] + ll[1];
  const float o2 = d2 * rs * gg[2] + ll[2];
  const float o3 = d3 * rs * gg[3] + ll[3];
  if (FINAL) {
    f32x4 o = { o0, o1, o2, o3 };
    *(f32x4*)((float*)out + (size_t)t * 256 + c0) = o;
  } else {
    u16x4 o = { f2bf(o0), f2bf(o1), f2bf(o2), f2bf(o3) };
    *(u16x4*)((unsigned short*)out + (size_t)t * 256 + c0) = o;
  }
}

// ---------------- launch ----------------
extern "C" void kernel_launch(void* const* d_in, const int* in_sizes, int n_in,
                              void* d_out, int out_size, void* d_ws, size_t ws_size,
                              hipStream_t stream) {
  (void)in_sizes; (void)n_in; (void)out_size; (void)ws_size;
  const float* x   = (const float*)d_in[0];
  const float* nw  = (const float*)d_in[1];
  const int*   esrc = (const int*)d_in[2];
  const int*   etgt = (const int*)d_in[3];
  const float* Wr0 = (const float*)d_in[4];
  const float* Ws0 = (const float*)d_in[5];
  const float* Wb0 = (const float*)d_in[6];
  const float* g0  = (const float*)d_in[7];
  const float* b0  = (const float*)d_in[8];
  const float* Wr1 = (const float*)d_in[9];
  const float* Ws1 = (const float*)d_in[10];
  const float* Wb1 = (const float*)d_in[11];
  const float* g1  = (const float*)d_in[12];
  const float* b1  = (const float*)d_in[13];

  char* p = (char*)d_ws;
  auto carve = [&](size_t bytes) {
    char* q = p;
    p += (bytes + 511) & ~(size_t)511;
    return q;
  };
  unsigned short* Y   = (unsigned short*)carve((size_t)M_PAD * N_CAT * 2);  // 231.2 MB
  unsigned short* xb  = (unsigned short*)carve((size_t)M_PAD * D_IN * 2);   //  77.1 MB
  unsigned short* h   = (unsigned short*)carve((size_t)M_PAD * D_H * 2);    //  25.7 MB
  unsigned short* Wt0 = (unsigned short*)carve((size_t)N_CAT * D_IN * 2);
  unsigned short* Wt1 = (unsigned short*)carve((size_t)N_CAT * D_H * 2);
  int*   deg     = (int*)carve((size_t)R_REL * N_NODES * 4);
  int*   pdeg    = (int*)carve((size_t)N_NODES * 4);
  int*   cursor  = (int*)carve((size_t)N_NODES * 4);
  int*   nodeptr = (int*)carve((size_t)(N_NODES + 1) * 4);
  int*   bsum    = (int*)carve((size_t)NCHUNK * 4);
  int*   chunkoff= (int*)carve((size_t)NCHUNK * 4);
  int2*  e2      = (int2*)carve((size_t)E_PAD_MAX * 8);
  int2*  scN     = (int2*)carve((size_t)N_NODES * 8);

  // CSR build (node-major; shared by both layers)
  hipMemsetAsync(deg, 0, (size_t)R_REL * N_NODES * 4, stream);
  hipMemsetAsync(cursor, 0, (size_t)N_NODES * 4, stream);
  hipMemsetAsync(e2, 0, (size_t)E_PAD_MAX * 8, stream);   // pad slots -> {src0, w=0}
  k_deg<<<(R_REL * E_EDGES + 255) / 256, 256, 0, stream>>>(etgt, deg);
  k_ndeg<<<(N_NODES + 255) / 256, 256, 0, stream>>>(deg, pdeg);
  k_scan1<<<NCHUNK, 256, 0, stream>>>(pdeg, nodeptr, bsum);
  k_scan2<<<1, 64, 0, stream>>>(bsum, chunkoff, nodeptr);
  k_scan3<<<NCHUNK, 256, 0, stream>>>(chunkoff, nodeptr);
  k_prep<<<(N_NODES + 255) / 256, 256, 0, stream>>>(nodeptr, scN);
  k_fill<<<(R_REL * E_EDGES + 255) / 256, 256, 0, stream>>>(esrc, etgt, nw, nodeptr,
                                                            deg, cursor, e2);
  // conversions
  k_cvt_x<<<(N_NODES * D_IN / 4 + 255) / 256, 256, 0, stream>>>(x, xb);
  k_cvt_w<<<(N_CAT * D_IN + 255) / 256, 256, 0, stream>>>(Ws0, Wr0, Wt0, D_IN);
  k_cvt_w<<<(N_CAT * D_H + 255) / 256, 256, 0, stream>>>(Ws1, Wr1, Wt1, D_H);

  // layer 0
  k_gemm<<<T_TOT256, 512, 0, stream>>>(xb, Wt0, Y, D_IN);
  k_gather_ln<0><<<N_NODES / 4, 256, 0, stream>>>(Y, scN, e2, Wb0, g0, b0, h);
  // layer 1
  k_gemm<<<T_TOT256, 512, 0, stream>>>(h, Wt1, Y, D_H);
  k_gather_ln<1><<<N_NODES / 4, 256, 0, stream>>>(Y, scN, e2, Wb1, g1, b1, d_out);
}

// Round 2
// 803.210 us; speedup vs baseline: 1.0306x; 1.0306x over previous
//
#include <hip/hip_runtime.h>
#include <stdint.h>

#define N_NODES 50000
#define M_PAD   50176   // 196*256
#define R_REL   8
#define E_EDGES 100000
#define D_IN    768
#define D_H     256
#define N_CAT   2304    // 9*256 : [self | rel0..rel7]
#define LN_EPS  1e-5f

#define TILES_M256 196
#define TILES_N256 9
#define T_TOT256   1764   // 196*9
#define NCHUNK  49        // ceil(50000/1024)
#define EP_STRIDE 68      // epilogue repack row stride (u16): bank-conflict-free
#define E_PAD_MAX 960000  // 800k edges + <=150k pad slots

typedef __attribute__((ext_vector_type(8))) __bf16        bf16x8;
typedef __attribute__((ext_vector_type(4))) float         f32x4;
typedef __attribute__((ext_vector_type(8))) unsigned short u16x8;
typedef __attribute__((ext_vector_type(4))) unsigned short u16x4;
typedef __attribute__((ext_vector_type(4))) int            i32x4;

__device__ __forceinline__ float bf2f(unsigned short u) {
  union { float f; uint32_t i; } c; c.i = ((uint32_t)u) << 16; return c.f;
}
__device__ __forceinline__ unsigned short f2bf(float f) {
  uint32_t x = __float_as_uint(f);
  uint32_t r = (x + 0x7fffu + ((x >> 16) & 1u)) >> 16;   // RNE
  return (unsigned short)r;
}

__device__ __forceinline__ void gload_lds16(const void* g, uint32_t lds_off) {
  __builtin_amdgcn_global_load_lds(
      (const __attribute__((address_space(1))) void*)(uintptr_t)g,
      (__attribute__((address_space(3))) void*)(uintptr_t)lds_off, 16, 0, 0);
}

// ---------------- CSR build (node-major, relations flattened) ----------------
__global__ void k_deg(const int* __restrict__ tgt, int* __restrict__ deg) {
  int e = blockIdx.x * 256 + threadIdx.x;
  if (e >= R_REL * E_EDGES) return;
  int r = e / E_EDGES;
  atomicAdd(&deg[r * N_NODES + tgt[e]], 1);
}

// per-node total degree, padded to multiple of 4
__global__ void k_ndeg(const int* __restrict__ deg, int* __restrict__ pdeg) {
  int t = blockIdx.x * 256 + threadIdx.x;
  if (t >= N_NODES) return;
  int s = 0;
#pragma unroll
  for (int r = 0; r < R_REL; ++r) s += deg[r * N_NODES + t];
  pdeg[t] = (s + 3) & ~3;
}

__global__ __launch_bounds__(256)
void k_scan1(const int* __restrict__ deg, int* __restrict__ rowptr,
             int* __restrict__ bsum) {
  __shared__ int wtot[4];
  const int chunk = blockIdx.x, tid = threadIdx.x;
  const int wave = tid >> 6, lane = tid & 63;
  const int i0 = chunk * 1024 + tid * 4;
  int v0 = 0, v1 = 0, v2 = 0, v3 = 0;
  const int* d = deg;
  if (chunk != NCHUNK - 1) {
    i32x4 v = *(const i32x4*)(d + i0);
    v0 = v[0]; v1 = v[1]; v2 = v[2]; v3 = v[3];
  } else {
    if (i0 + 0 < N_NODES) v0 = d[i0 + 0];
    if (i0 + 1 < N_NODES) v1 = d[i0 + 1];
    if (i0 + 2 < N_NODES) v2 = d[i0 + 2];
    if (i0 + 3 < N_NODES) v3 = d[i0 + 3];
  }
  const int tsum = v0 + v1 + v2 + v3;
  int inc = tsum;
#pragma unroll
  for (int off = 1; off < 64; off <<= 1) {
    int t = __shfl_up(inc, off, 64);
    if (lane >= off) inc += t;
  }
  if (lane == 63) wtot[wave] = inc;
  __syncthreads();
  int woff = 0;
#pragma unroll
  for (int w = 0; w < 4; ++w) woff += (w < wave) ? wtot[w] : 0;
  int excl = woff + inc - tsum;
  int* rp = rowptr;
  if (i0 + 0 < N_NODES) rp[i0 + 0] = excl;
  if (i0 + 1 < N_NODES) rp[i0 + 1] = excl + v0;
  if (i0 + 2 < N_NODES) rp[i0 + 2] = excl + v0 + v1;
  if (i0 + 3 < N_NODES) rp[i0 + 3] = excl + v0 + v1 + v2;
  if (tid == 0) bsum[chunk] = wtot[0] + wtot[1] + wtot[2] + wtot[3];
}

__global__ __launch_bounds__(64)
void k_scan2(const int* __restrict__ bsum, int* __restrict__ chunkoff,
             int* __restrict__ rowptr) {
  const int lane = threadIdx.x & 63;
  int v = (lane < NCHUNK) ? bsum[lane] : 0;
  int inc = v;
#pragma unroll
  for (int off = 1; off < 64; off <<= 1) {
    int t = __shfl_up(inc, off, 64);
    if (lane >= off) inc += t;
  }
  if (lane < NCHUNK) chunkoff[lane] = inc - v;   // exclusive
  if (lane == NCHUNK - 1) rowptr[N_NODES] = inc;
}

__global__ __launch_bounds__(256)
void k_scan3(const int* __restrict__ chunkoff, int* __restrict__ rowptr) {
  const int chunk = blockIdx.x;
  if (chunk == 0) return;
  const int off = chunkoff[chunk];
  const int i0 = chunk * 1024 + threadIdx.x * 4;
#pragma unroll
  for (int j = 0; j < 4; ++j)
    if (i0 + j < N_NODES) rowptr[i0 + j] += off;
}

// per-node {start, padded_count}
__global__ void k_prep(const int* __restrict__ nodeptr, int2* __restrict__ scN) {
  int t = blockIdx.x * 256 + threadIdx.x;
  if (t >= N_NODES) return;
  scN[t] = make_int2(nodeptr[t], nodeptr[t + 1] - nodeptr[t]);
}

// fill flattened adjacency: e2[slot] = {src | rel<<16, nw[src]/deg[rel][tgt]}
__global__ void k_fill(const int* __restrict__ src, const int* __restrict__ tgt,
                       const float* __restrict__ nw, const int* __restrict__ nodeptr,
                       const int* __restrict__ deg, int* __restrict__ cursor,
                       int2* __restrict__ e2) {
  int e = blockIdx.x * 256 + threadIdx.x;
  if (e >= R_REL * E_EDGES) return;
  int r = e / E_EDGES;
  int t = tgt[e], s = src[e];
  int pos = atomicAdd(&cursor[t], 1);
  int slot = nodeptr[t] + pos;
  float w = nw[s] / (float)deg[r * N_NODES + t];
  e2[slot] = make_int2(s | (r << 16), __float_as_int(w));
}

// ---------------- conversions ----------------
__global__ void k_cvt_x(const float* __restrict__ x, unsigned short* __restrict__ xb) {
  const size_t i = ((size_t)blockIdx.x * 256 + threadIdx.x) * 4;
  if (i >= (size_t)N_NODES * D_IN) return;
  const f32x4 v = *(const f32x4*)(x + i);
  u16x4 o = { f2bf(v[0]), f2bf(v[1]), f2bf(v[2]), f2bf(v[3]) };
  *(u16x4*)(xb + i) = o;
}

// Wt[n][k] = n<256 ? Wself[k][n] : Wrel[(n-256)>>8][k][n&255]   (bf16, [N_CAT][K])
__global__ void k_cvt_w(const float* __restrict__ Ws, const float* __restrict__ Wr,
                        unsigned short* __restrict__ Wt, int K) {
  int idx = blockIdx.x * 256 + threadIdx.x;
  if (idx >= N_CAT * K) return;
  int n = idx / K, k = idx - n * K;
  float v = (n < 256) ? Ws[k * 256 + n]
                      : Wr[(size_t)((n - 256) >> 8) * K * 256 + k * 256 + (n & 255)];
  Wt[idx] = f2bf(v);
}

// ---------------- bf16 MFMA GEMM, 256x256 tile, BK=64, 8-phase counted-vmcnt ----------------
// C[M_PAD,N_CAT] = A @ Bt^T. 8 waves (2M x 4N), per-wave 128x64 output (acc[8][4]).
// LDS: bufA[2][256][64] @0, bufB[2][256][64] @65536 (128 KiB). Rows are 128 B =
// 8 x 16B chunks; chunk c of row r lives at slot c^(r&7) -> staging (linear dest,
// pre-swizzled global src) and fragment ds_read_b128 are both bank-conflict-free.
//
// LDS-read budget (the r1 lesson): MFMA per K-tile per CU = 2484 cyc; LDS reads
// must stay under that. B fragments are loaded ONCE per K-tile (phase 0) and held
// in registers -> 24 ds_read_b128/wave/K-tile (196KB read + 64KB write ~ 2030 cyc).
//
// Phase q (q=0..3) of K-tile t computes mi={2q,2q+1} x nj=0..3 x kk=0..1 (16 MFMA)
// and ds_reads A rows {wmRow+32q..+31}; B[cur] LDS is dead after phase 0.
// Staging schedule (target region must be dead by end of previous phase):
//   q0: A-halfY(t+1) rows {64-127,192-255} -> other buffer (dead since tile start)
//   q1: B(t+2) rows 0-127   -> cur buffer B (dead after q0: bfr in regs)
//   q2: B(t+2) rows 128-255 + A-halfX(t+2) rows {0-63,128-191} (dead after q1)
// Boundary: s_waitcnt vmcnt(6) -> only t+2's 6 loads remain in flight; certifies
// buffer[t+1] complete. Never vmcnt(0) in steady state (drains only at tail).
__global__ __launch_bounds__(512, 2)
void k_gemm(const unsigned short* __restrict__ A, const unsigned short* __restrict__ Bt,
            unsigned short* __restrict__ C, int K) {
  __shared__ __align__(16) char smem[131072];

  // bijective XCD swizzle (nwg=1764, nwg%8=4) — m204 variant
  const int bid = blockIdx.x;
  const int xcd = bid & 7, idx = bid >> 3;
  const int q9 = T_TOT256 >> 3, rr = T_TOT256 & 7;       // 220, 4
  const int wg = (xcd < rr ? xcd * (q9 + 1)
                           : rr * (q9 + 1) + (xcd - rr) * q9) + idx;
  const int tm9 = wg / 9;
  const int tileM = tm9 * 256;
  const int tileN = (wg - tm9 * 9) * 256;

  const int tid  = threadIdx.x;
  const int wave = tid >> 6, lane = tid & 63;
  const int wmRow = (wave >> 2) * 128;                   // 2 M-waves
  const int wnRow = (wave & 3) * 64;                     // 4 N-waves
  const int c16 = lane & 15, fph = lane >> 4, x7 = lane & 7;

  // staging lanes: 512 threads cover one 64-row round (8 KiB) per gload
  const int srow = tid >> 3, sl8 = tid & 7;
  const int cch = sl8 ^ (srow & 7);                      // pre-swizzled global chunk
  const unsigned short* gA0 = A  + (size_t)(tileM + srow) * K + cch * 8;
  const unsigned short* gB0 = Bt + (size_t)(tileN + srow) * K + cch * 8;
  const uint32_t ldsA = (uint32_t)(uintptr_t)smem;
  const uint32_t ldsB = ldsA + 65536u;
  const uint32_t linA = (uint32_t)(srow * 128 + sl8 * 16);

#define STA(R0, tt) gload_lds16(gA0 + (size_t)(R0) * K + (size_t)(tt) * 64, \
                                ldsA + (uint32_t)(((tt) & 1) * 32768) + (uint32_t)((R0) * 128) + linA)
#define STB(R0, tt) gload_lds16(gB0 + (size_t)(R0) * K + (size_t)(tt) * 64, \
                                ldsB + (uint32_t)(((tt) & 1) * 32768) + (uint32_t)((R0) * 128) + linA)

  f32x4 acc[8][4] = {};

  // fragment read bases (row stride 128 B; chunk c of row r at slot c^(r&7), r&7==lane&7)
  const char* pA = smem          + (wmRow + c16) * 128;
  const char* pB = smem + 65536  + (wnRow + c16) * 128;

  const int nk = K >> 6;                                  // 12 (K=768) or 4 (K=256)

  // prologue: tile0 complete (8) + tile1 B (4) + tile1 A-halfX (2)
  STA(0, 0); STA(128, 0); STA(64, 0); STA(192, 0);
  STB(0, 0); STB(64, 0);  STB(128, 0); STB(192, 0);
  if (nk > 1) {
    STB(0, 1); STB(64, 1); STB(128, 1); STB(192, 1);
    STA(0, 1); STA(128, 1);
    asm volatile("s_waitcnt vmcnt(6)" ::: "memory");      // tile0 landed
  } else {
    asm volatile("s_waitcnt vmcnt(0)" ::: "memory");
  }
  asm volatile("s_barrier" ::: "memory");

  for (int t = 0; t < nk; ++t) {
    const uint32_t bA = (uint32_t)(t & 1) * 32768u;
    bf16x8 bfr[2][4];                                     // held across all 4 phases
#pragma unroll
    for (int q = 0; q < 4; ++q) {
      bf16x8 af[2];
#pragma unroll
      for (int kk = 0; kk < 2; ++kk) {
        const int sA = ((kk * 4 + fph) ^ x7) * 16;
        af[kk] = *(const bf16x8*)(pA + bA + (q * 2 + 0) * 2048 + sA);
      }
      bf16x8 af1[2];
#pragma unroll
      for (int kk = 0; kk < 2; ++kk) {
        const int sA = ((kk * 4 + fph) ^ x7) * 16;
        af1[kk] = *(const bf16x8*)(pA + bA + (q * 2 + 1) * 2048 + sA);
      }
      if (q == 0) {
#pragma unroll
        for (int kk = 0; kk < 2; ++kk) {
          const int sA = ((kk * 4 + fph) ^ x7) * 16;
#pragma unroll
          for (int nj = 0; nj < 4; ++nj)
            bfr[kk][nj] = *(const bf16x8*)(pB + bA + nj * 2048 + sA);
        }
      }
      // staging (see schedule comment above)
      if (q == 0 && t + 1 < nk) { STA(64, t + 1); STA(192, t + 1); }
      if (q == 1 && t + 2 < nk) { STB(0, t + 2); STB(64, t + 2); }
      if (q == 2 && t + 2 < nk) { STB(128, t + 2); STB(192, t + 2); STA(0, t + 2); STA(128, t + 2); }
      if (q == 0) asm volatile("s_waitcnt lgkmcnt(8)" ::: "memory");  // 12-read phase: early drain
      asm volatile("s_barrier" ::: "memory");
      asm volatile("s_waitcnt lgkmcnt(0)" ::: "memory");
      __builtin_amdgcn_s_setprio(1);
#pragma unroll
      for (int nj = 0; nj < 4; ++nj)
#pragma unroll
        for (int kk = 0; kk < 2; ++kk)
          acc[q * 2 + 0][nj] = __builtin_amdgcn_mfma_f32_16x16x32_bf16(
              af[kk], bfr[kk][nj], acc[q * 2 + 0][nj], 0, 0, 0);
#pragma unroll
      for (int nj = 0; nj < 4; ++nj)
#pragma unroll
        for (int kk = 0; kk < 2; ++kk)
          acc[q * 2 + 1][nj] = __builtin_amdgcn_mfma_f32_16x16x32_bf16(
              af1[kk], bfr[kk][nj], acc[q * 2 + 1][nj], 0, 0, 0);
      __builtin_amdgcn_s_setprio(0);
      if (q < 3) asm volatile("s_barrier" ::: "memory");
    }
    if (t + 1 < nk) {
      if (t + 2 < nk) asm volatile("s_waitcnt vmcnt(6)" ::: "memory");
      else            asm volatile("s_waitcnt vmcnt(0)" ::: "memory");
      asm volatile("s_barrier" ::: "memory");
    }
  }
  asm volatile("s_waitcnt vmcnt(0)" ::: "memory");        // tail: already drained
  asm volatile("s_barrier" ::: "memory");                 // GEMM LDS dead -> reuse

#undef STA
#undef STB

  // epilogue: per-wave 128x64 output in two 64-row passes via LDS repack
  unsigned short* st = (unsigned short*)smem + wave * (64 * EP_STRIDE);
  const int rq4 = (lane >> 4) * 4, cq = lane & 15;
#pragma unroll
  for (int half = 0; half < 2; ++half) {
#pragma unroll
    for (int i = 0; i < 4; ++i)
#pragma unroll
      for (int j = 0; j < 4; ++j)
#pragma unroll
        for (int p = 0; p < 4; ++p)
          st[(i * 16 + rq4 + p) * EP_STRIDE + j * 16 + cq] = f2bf(acc[half * 4 + i][j][p]);
#pragma unroll
    for (int pass = 0; pass < 8; ++pass) {
      const int row = pass * 8 + (lane >> 3);
      const unsigned short* rp_ = st + row * EP_STRIDE + (lane & 7) * 8;
      u16x4 lo = *(const u16x4*)(rp_);
      u16x4 hi = *(const u16x4*)(rp_ + 4);
      u16x8 v = { lo[0], lo[1], lo[2], lo[3], hi[0], hi[1], hi[2], hi[3] };
      size_t off = (size_t)(tileM + wmRow + half * 64 + row) * N_CAT + tileN + wnRow + (lane & 7) * 8;
      *(u16x8*)(C + off) = v;
    }
  }
}

// ---------------- fused gather + mean + self + bias + ReLU + LayerNorm ----------------
// one wave per node, 4 channels/lane; single flattened edge loop, 4 edges in flight.
template <int FINAL>
__global__ __launch_bounds__(256)
void k_gather_ln(const unsigned short* __restrict__ Y, const int2* __restrict__ scN,
                 const int2* __restrict__ e2, const float* __restrict__ bias,
                 const float* __restrict__ g, const float* __restrict__ bln,
                 void* __restrict__ out) {
  const int wave = threadIdx.x >> 6, lane = threadIdx.x & 63;
  const int t = blockIdx.x * 4 + wave;
  if (t >= N_NODES) return;
  const int c0 = lane * 4;

  float a0, a1, a2, a3;
  {
    u16x4 sv = *(const u16x4*)(Y + (size_t)t * N_CAT + c0);
    f32x4 bb = *(const f32x4*)(bias + c0);
    a0 = bf2f(sv[0]) + bb[0];
    a1 = bf2f(sv[1]) + bb[1];
    a2 = bf2f(sv[2]) + bb[2];
    a3 = bf2f(sv[3]) + bb[3];
  }

  const int2 s = scN[t];                    // {start, padded_cnt (x4)}
  const int2* ep = e2 + s.x;
  for (int idx = 0; idx < s.y; idx += 4) {
    const int2 p0 = ep[idx + 0];
    const int2 p1 = ep[idx + 1];
    const int2 p2 = ep[idx + 2];
    const int2 p3 = ep[idx + 3];
    // addr: Y + src*2304 + (rel+1)*256 + c0 ; pad slots are {0,w=0} -> add 0
    const unsigned short* y0 = Y + (size_t)(p0.x & 0xFFFF) * N_CAT + (((p0.x >> 16) + 1) << 8) + c0;
    const unsigned short* y1 = Y + (size_t)(p1.x & 0xFFFF) * N_CAT + (((p1.x >> 16) + 1) << 8) + c0;
    const unsigned short* y2 = Y + (size_t)(p2.x & 0xFFFF) * N_CAT + (((p2.x >> 16) + 1) << 8) + c0;
    const unsigned short* y3 = Y + (size_t)(p3.x & 0xFFFF) * N_CAT + (((p3.x >> 16) + 1) << 8) + c0;
    u16x4 v0 = *(const u16x4*)y0;
    u16x4 v1 = *(const u16x4*)y1;
    u16x4 v2 = *(const u16x4*)y2;
    u16x4 v3 = *(const u16x4*)y3;
    const float w0 = __int_as_float(p0.y), w1 = __int_as_float(p1.y);
    const float w2 = __int_as_float(p2.y), w3 = __int_as_float(p3.y);
    a0 += w0 * bf2f(v0[0]) + w1 * bf2f(v1[0]) + w2 * bf2f(v2[0]) + w3 * bf2f(v3[0]);
    a1 += w0 * bf2f(v0[1]) + w1 * bf2f(v1[1]) + w2 * bf2f(v2[1]) + w3 * bf2f(v3[1]);
    a2 += w0 * bf2f(v0[2]) + w1 * bf2f(v1[2]) + w2 * bf2f(v2[2]) + w3 * bf2f(v3[2]);
    a3 += w0 * bf2f(v0[3]) + w1 * bf2f(v1[3]) + w2 * bf2f(v2[3]) + w3 * bf2f(v3[3]);
  }

  a0 = fmaxf(a0, 0.f); a1 = fmaxf(a1, 0.f); a2 = fmaxf(a2, 0.f); a3 = fmaxf(a3, 0.f);

  float s1 = (a0 + a1) + (a2 + a3);
#pragma unroll
  for (int off = 32; off > 0; off >>= 1) s1 += __shfl_xor(s1, off, 64);
  const float mu = s1 * (1.f / 256.f);
  const float d0 = a0 - mu, d1 = a1 - mu, d2 = a2 - mu, d3 = a3 - mu;
  float s2 = (d0 * d0 + d1 * d1) + (d2 * d2 + d3 * d3);
#pragma unroll
  for (int off = 32; off > 0; off >>= 1) s2 += __shfl_xor(s2, off, 64);
  const float rs = rsqrtf(s2 * (1.f / 256.f) + LN_EPS);

  f32x4 gg = *(const f32x4*)(g + c0);
  f32x4 ll = *(const f32x4*)(bln + c0);
  const float o0 = d0 * rs * gg[0] + ll[0];
  const float o1 = d1 * rs * gg[1] + ll[1];
  const float o2 = d2 * rs * gg[2] + ll[2];
  const float o3 = d3 * rs * gg[3] + ll[3];
  if (FINAL) {
    f32x4 o = { o0, o1, o2, o3 };
    *(f32x4*)((float*)out + (size_t)t * 256 + c0) = o;
  } else {
    u16x4 o = { f2bf(o0), f2bf(o1), f2bf(o2), f2bf(o3) };
    *(u16x4*)((unsigned short*)out + (size_t)t * 256 + c0) = o;
  }
}

// ---------------- launch ----------------
extern "C" void kernel_launch(void* const* d_in, const int* in_sizes, int n_in,
                              void* d_out, int out_size, void* d_ws, size_t ws_size,
                              hipStream_t stream) {
  (void)in_sizes; (void)n_in; (void)out_size; (void)ws_size;
  const float* x   = (const float*)d_in[0];
  const float* nw  = (const float*)d_in[1];
  const int*   esrc = (const int*)d_in[2];
  const int*   etgt = (const int*)d_in[3];
  const float* Wr0 = (const float*)d_in[4];
  const float* Ws0 = (const float*)d_in[5];
  const float* Wb0 = (const float*)d_in[6];
  const float* g0  = (const float*)d_in[7];
  const float* b0  = (const float*)d_in[8];
  const float* Wr1 = (const float*)d_in[9];
  const float* Ws1 = (const float*)d_in[10];
  const float* Wb1 = (const float*)d_in[11];
  const float* g1  = (const float*)d_in[12];
  const float* b1  = (const float*)d_in[13];

  char* p = (char*)d_ws;
  auto carve = [&](size_t bytes) {
    char* q = p;
    p += (bytes + 511) & ~(size_t)511;
    return q;
  };
  unsigned short* Y   = (unsigned short*)carve((size_t)M_PAD * N_CAT * 2);  // 231.2 MB
  unsigned short* xb  = (unsigned short*)carve((size_t)M_PAD * D_IN * 2);   //  77.1 MB
  unsigned short* h   = (unsigned short*)carve((size_t)M_PAD * D_H * 2);    //  25.7 MB
  unsigned short* Wt0 = (unsigned short*)carve((size_t)N_CAT * D_IN * 2);
  unsigned short* Wt1 = (unsigned short*)carve((size_t)N_CAT * D_H * 2);
  int*   deg     = (int*)carve((size_t)R_REL * N_NODES * 4);
  int*   pdeg    = (int*)carve((size_t)N_NODES * 4);
  int*   cursor  = (int*)carve((size_t)N_NODES * 4);
  int*   nodeptr = (int*)carve((size_t)(N_NODES + 1) * 4);
  int*   bsum    = (int*)carve((size_t)NCHUNK * 4);
  int*   chunkoff= (int*)carve((size_t)NCHUNK * 4);
  int2*  e2      = (int2*)carve((size_t)E_PAD_MAX * 8);
  int2*  scN     = (int2*)carve((size_t)N_NODES * 8);

  // CSR build (node-major; shared by both layers)
  hipMemsetAsync(deg, 0, (size_t)R_REL * N_NODES * 4, stream);
  hipMemsetAsync(cursor, 0, (size_t)N_NODES * 4, stream);
  hipMemsetAsync(e2, 0, (size_t)E_PAD_MAX * 8, stream);   // pad slots -> {src0, w=0}
  k_deg<<<(R_REL * E_EDGES + 255) / 256, 256, 0, stream>>>(etgt, deg);
  k_ndeg<<<(N_NODES + 255) / 256, 256, 0, stream>>>(deg, pdeg);
  k_scan1<<<NCHUNK, 256, 0, stream>>>(pdeg, nodeptr, bsum);
  k_scan2<<<1, 64, 0, stream>>>(bsum, chunkoff, nodeptr);
  k_scan3<<<NCHUNK, 256, 0, stream>>>(chunkoff, nodeptr);
  k_prep<<<(N_NODES + 255) / 256, 256, 0, stream>>>(nodeptr, scN);
  k_fill<<<(R_REL * E_EDGES + 255) / 256, 256, 0, stream>>>(esrc, etgt, nw, nodeptr,
                                                            deg, cursor, e2);
  // conversions
  k_cvt_x<<<(N_NODES * D_IN / 4 + 255) / 256, 256, 0, stream>>>(x, xb);
  k_cvt_w<<<(N_CAT * D_IN + 255) / 256, 256, 0, stream>>>(Ws0, Wr0, Wt0, D_IN);
  k_cvt_w<<<(N_CAT * D_H + 255) / 256, 256, 0, stream>>>(Ws1, Wr1, Wt1, D_H);

  // layer 0
  k_gemm<<<T_TOT256, 512, 0, stream>>>(xb, Wt0, Y, D_IN);
  k_gather_ln<0><<<N_NODES / 4, 256, 0, stream>>>(Y, scN, e2, Wb0, g0, b0, h);
  // layer 1
  k_gemm<<<T_TOT256, 512, 0, stream>>>(h, Wt1, Y, D_H);
  k_gather_ln<1><<<N_NODES / 4, 256, 0, stream>>>(Y, scN, e2, Wb1, g1, b1, d_out);
}

// Round 3
// 783.309 us; speedup vs baseline: 1.0568x; 1.0254x over previous
//
#include <hip/hip_runtime.h>
#include <stdint.h>

#define N_NODES 50000
#define M_PAD   50176   // 196*256
#define R_REL   8
#define E_EDGES 100000
#define D_IN    768
#define D_H     256
#define N_CAT   2304    // 9*256 : [self | rel0..rel7]
#define LN_EPS  1e-5f

#define TILES_M256 196
#define TILES_N256 9
#define T_TOT256   1764   // 196*9
#define NCHUNK  49        // ceil(50000/1024)
#define EP_STRIDE 68      // epilogue repack row stride (u16): bank-conflict-free
#define E_PAD_MAX 960000  // 800k edges + <=150k pad slots

typedef __attribute__((ext_vector_type(8))) __bf16        bf16x8;
typedef __attribute__((ext_vector_type(4))) float         f32x4;
typedef __attribute__((ext_vector_type(8))) unsigned short u16x8;
typedef __attribute__((ext_vector_type(4))) unsigned short u16x4;
typedef __attribute__((ext_vector_type(4))) int            i32x4;

__device__ __forceinline__ float bf2f(unsigned short u) {
  union { float f; uint32_t i; } c; c.i = ((uint32_t)u) << 16; return c.f;
}
__device__ __forceinline__ unsigned short f2bf(float f) {
  uint32_t x = __float_as_uint(f);
  uint32_t r = (x + 0x7fffu + ((x >> 16) & 1u)) >> 16;   // RNE
  return (unsigned short)r;
}

__device__ __forceinline__ void gload_lds16(const void* g, uint32_t lds_off) {
  __builtin_amdgcn_global_load_lds(
      (const __attribute__((address_space(1))) void*)(uintptr_t)g,
      (__attribute__((address_space(3))) void*)(uintptr_t)lds_off, 16, 0, 0);
}

// ---------------- CSR build (node-major, relations flattened) ----------------
__global__ void k_deg(const int* __restrict__ tgt, int* __restrict__ deg) {
  int e = blockIdx.x * 256 + threadIdx.x;
  if (e >= R_REL * E_EDGES) return;
  int r = e / E_EDGES;
  atomicAdd(&deg[r * N_NODES + tgt[e]], 1);
}

// per-node total degree, padded to multiple of 4
__global__ void k_ndeg(const int* __restrict__ deg, int* __restrict__ pdeg) {
  int t = blockIdx.x * 256 + threadIdx.x;
  if (t >= N_NODES) return;
  int s = 0;
#pragma unroll
  for (int r = 0; r < R_REL; ++r) s += deg[r * N_NODES + t];
  pdeg[t] = (s + 3) & ~3;
}

__global__ __launch_bounds__(256)
void k_scan1(const int* __restrict__ deg, int* __restrict__ rowptr,
             int* __restrict__ bsum) {
  __shared__ int wtot[4];
  const int chunk = blockIdx.x, tid = threadIdx.x;
  const int wave = tid >> 6, lane = tid & 63;
  const int i0 = chunk * 1024 + tid * 4;
  int v0 = 0, v1 = 0, v2 = 0, v3 = 0;
  const int* d = deg;
  if (chunk != NCHUNK - 1) {
    i32x4 v = *(const i32x4*)(d + i0);
    v0 = v[0]; v1 = v[1]; v2 = v[2]; v3 = v[3];
  } else {
    if (i0 + 0 < N_NODES) v0 = d[i0 + 0];
    if (i0 + 1 < N_NODES) v1 = d[i0 + 1];
    if (i0 + 2 < N_NODES) v2 = d[i0 + 2];
    if (i0 + 3 < N_NODES) v3 = d[i0 + 3];
  }
  const int tsum = v0 + v1 + v2 + v3;
  int inc = tsum;
#pragma unroll
  for (int off = 1; off < 64; off <<= 1) {
    int t = __shfl_up(inc, off, 64);
    if (lane >= off) inc += t;
  }
  if (lane == 63) wtot[wave] = inc;
  __syncthreads();
  int woff = 0;
#pragma unroll
  for (int w = 0; w < 4; ++w) woff += (w < wave) ? wtot[w] : 0;
  int excl = woff + inc - tsum;
  int* rp = rowptr;
  if (i0 + 0 < N_NODES) rp[i0 + 0] = excl;
  if (i0 + 1 < N_NODES) rp[i0 + 1] = excl + v0;
  if (i0 + 2 < N_NODES) rp[i0 + 2] = excl + v0 + v1;
  if (i0 + 3 < N_NODES) rp[i0 + 3] = excl + v0 + v1 + v2;
  if (tid == 0) bsum[chunk] = wtot[0] + wtot[1] + wtot[2] + wtot[3];
}

__global__ __launch_bounds__(64)
void k_scan2(const int* __restrict__ bsum, int* __restrict__ chunkoff,
             int* __restrict__ rowptr) {
  const int lane = threadIdx.x & 63;
  int v = (lane < NCHUNK) ? bsum[lane] : 0;
  int inc = v;
#pragma unroll
  for (int off = 1; off < 64; off <<= 1) {
    int t = __shfl_up(inc, off, 64);
    if (lane >= off) inc += t;
  }
  if (lane < NCHUNK) chunkoff[lane] = inc - v;   // exclusive
  if (lane == NCHUNK - 1) rowptr[N_NODES] = inc;
}

__global__ __launch_bounds__(256)
void k_scan3(const int* __restrict__ chunkoff, int* __restrict__ rowptr) {
  const int chunk = blockIdx.x;
  if (chunk == 0) return;
  const int off = chunkoff[chunk];
  const int i0 = chunk * 1024 + threadIdx.x * 4;
#pragma unroll
  for (int j = 0; j < 4; ++j)
    if (i0 + j < N_NODES) rowptr[i0 + j] += off;
}

// per-node {start, padded_count}
__global__ void k_prep(const int* __restrict__ nodeptr, int2* __restrict__ scN) {
  int t = blockIdx.x * 256 + threadIdx.x;
  if (t >= N_NODES) return;
  scN[t] = make_int2(nodeptr[t], nodeptr[t + 1] - nodeptr[t]);
}

// fill flattened adjacency: e2[slot] = {src | rel<<16, nw[src]/deg[rel][tgt]}
__global__ void k_fill(const int* __restrict__ src, const int* __restrict__ tgt,
                       const float* __restrict__ nw, const int* __restrict__ nodeptr,
                       const int* __restrict__ deg, int* __restrict__ cursor,
                       int2* __restrict__ e2) {
  int e = blockIdx.x * 256 + threadIdx.x;
  if (e >= R_REL * E_EDGES) return;
  int r = e / E_EDGES;
  int t = tgt[e], s = src[e];
  int pos = atomicAdd(&cursor[t], 1);
  int slot = nodeptr[t] + pos;
  float w = nw[s] / (float)deg[r * N_NODES + t];
  e2[slot] = make_int2(s | (r << 16), __float_as_int(w));
}

// ---------------- conversions ----------------
__global__ void k_cvt_x(const float* __restrict__ x, unsigned short* __restrict__ xb) {
  const size_t i = ((size_t)blockIdx.x * 256 + threadIdx.x) * 4;
  if (i >= (size_t)N_NODES * D_IN) return;
  const f32x4 v = *(const f32x4*)(x + i);
  u16x4 o = { f2bf(v[0]), f2bf(v[1]), f2bf(v[2]), f2bf(v[3]) };
  *(u16x4*)(xb + i) = o;
}

// Wt[n][k] = n<256 ? Wself[k][n] : Wrel[(n-256)>>8][k][n&255]   (bf16, [N_CAT][K])
__global__ void k_cvt_w(const float* __restrict__ Ws, const float* __restrict__ Wr,
                        unsigned short* __restrict__ Wt, int K) {
  int idx = blockIdx.x * 256 + threadIdx.x;
  if (idx >= N_CAT * K) return;
  int n = idx / K, k = idx - n * K;
  float v = (n < 256) ? Ws[k * 256 + n]
                      : Wr[(size_t)((n - 256) >> 8) * K * 256 + k * 256 + (n & 255)];
  Wt[idx] = f2bf(v);
}

// ---------------- bf16 MFMA GEMM, 256x256 tile, BK=64, relaxed-lockstep pipeline ----
// C[M_PAD,N_CAT] = A @ Bt^T. 8 waves (2M x 4N), per-wave 128x64 output (acc[8][4]).
// LDS: bufA[2][256][64] @0, bufB[2][256][64] @65536 (128 KiB). Rows are 128 B =
// 8 x 16B chunks; chunk c of row r lives at slot c^(r&7) -> staging (linear dest,
// pre-swizzled global src) and fragment ds_read_b128 are both bank-conflict-free.
//
// r2 lesson: 8 barriers/tile lockstep all waves -> LDS drain (96 b128 x ~12cyc) and
// MFMA burst (621 cyc/SIMD) ALTERNATE instead of overlapping -> phase ~1725 cyc.
// This version: 3 barriers/tile; A-fragments register-pipelined one phase ahead;
// t-loop unrolled x2 (nk always even) so buffer parity / all LDS offsets are
// compile-time immediates and staging uses running row-pointers (+128/iter).
//
// Per tile t (parity u): [boundary barrier certified t data]
//   issue B(8)+Aq0(4)+Aq1(4) ds_reads; stage halfY(t+1)->other buf (dead)
//   MFMA q0 (waits bfr+a via compiler lgkm)  | barrier #1 (all B reads drained)
//   read Aq2; stage B(t+2)->cur B (dead after q0)
//   MFMA q1 (drains ALL t-start reads)       | barrier #2 (halfX reads drained)
//   read Aq3; stage halfX(t+2)->cur A rows 0-63/128-191 (dead after q1)
//   MFMA q2; MFMA q3
//   boundary: vmcnt(6) (per-tile stages: halfY 2, B 4, halfX 2 -> newest 6 = t+2)
__global__ __launch_bounds__(512, 2)
void k_gemm(const unsigned short* __restrict__ A, const unsigned short* __restrict__ Bt,
            unsigned short* __restrict__ C, int K) {
  __shared__ __align__(16) char smem[131072];

  // bijective XCD swizzle (nwg=1764, nwg%8=4) — m204 variant
  const int bid = blockIdx.x;
  const int xcd = bid & 7, idx = bid >> 3;
  const int q9 = T_TOT256 >> 3, rr = T_TOT256 & 7;       // 220, 4
  const int wg = (xcd < rr ? xcd * (q9 + 1)
                           : rr * (q9 + 1) + (xcd - rr) * q9) + idx;
  const int tm9 = wg / 9;
  const int tileM = tm9 * 256;
  const int tileN = (wg - tm9 * 9) * 256;

  const int tid  = threadIdx.x;
  const int wave = tid >> 6, lane = tid & 63;
  const int wmRow = (wave >> 2) * 128;                   // 2 M-waves
  const int wnRow = (wave & 3) * 64;                     // 4 N-waves
  const int c16 = lane & 15, fph = lane >> 4, x7 = lane & 7;

  // staging lanes: 512 threads cover one 64-row round (8 KiB) per gload
  const int srow = tid >> 3, sl8 = tid & 7;
  const int cch = sl8 ^ (srow & 7);                      // pre-swizzled global chunk
  const unsigned short* gA = A  + (size_t)(tileM + srow) * K + cch * 8;
  const unsigned short* gB = Bt + (size_t)(tileN + srow) * K + cch * 8;
  const unsigned short* gAr0 = gA;
  const unsigned short* gAr1 = gA + (size_t)64  * K;
  const unsigned short* gAr2 = gA + (size_t)128 * K;
  const unsigned short* gAr3 = gA + (size_t)192 * K;
  const unsigned short* gBr0 = gB;
  const unsigned short* gBr1 = gB + (size_t)64  * K;
  const unsigned short* gBr2 = gB + (size_t)128 * K;
  const unsigned short* gBr3 = gB + (size_t)192 * K;
  const uint32_t ldsA = (uint32_t)(uintptr_t)smem;
  const uint32_t ldsB = ldsA + 65536u;
  const uint32_t linA = (uint32_t)(srow * 128 + sl8 * 16);

  auto stA = [&](const unsigned short* p, uint32_t rowoff, int du, uint32_t par) {
    gload_lds16(p + du * 64, ldsA + par * 32768u + rowoff + linA);
  };
  auto stB = [&](const unsigned short* p, uint32_t rowoff, int du, uint32_t par) {
    gload_lds16(p + du * 64, ldsB + par * 32768u + rowoff + linA);
  };

  f32x4 acc[8][4] = {};

  // fragment read bases: addr = pX<kk> + bufParity*32768 + (2q+mi)*2048 (imm)
  const char* pAb = smem         + (wmRow + c16) * 128;
  const char* pBb = smem + 65536 + (wnRow + c16) * 128;
  const char* pA0 = pAb + ((fph)     ^ x7) * 16;   // kk=0
  const char* pA1 = pAb + ((4 + fph) ^ x7) * 16;   // kk=1
  const char* pB0 = pBb + ((fph)     ^ x7) * 16;
  const char* pB1 = pBb + ((4 + fph) ^ x7) * 16;

  const int nk = K >> 6;                                  // 12 (K=768) or 4 (K=256)

  // prologue: tile0 (8, oldest) + tile1 B (4) + tile1 A-halfX (2)
  stA(gAr0, 0, 0, 0); stA(gAr1, 8192, 0, 0); stA(gAr2, 16384, 0, 0); stA(gAr3, 24576, 0, 0);
  stB(gBr0, 0, 0, 0); stB(gBr1, 8192, 0, 0); stB(gBr2, 16384, 0, 0); stB(gBr3, 24576, 0, 0);
  if (nk > 1) {
    stB(gBr0, 0, 1, 1); stB(gBr1, 8192, 1, 1); stB(gBr2, 16384, 1, 1); stB(gBr3, 24576, 1, 1);
    stA(gAr0, 0, 1, 1); stA(gAr2, 16384, 1, 1);
    asm volatile("s_waitcnt vmcnt(6)" ::: "memory");      // tile0 landed
  } else {
    asm volatile("s_waitcnt vmcnt(0)" ::: "memory");
  }
  asm volatile("s_barrier" ::: "memory");

#define MM(a, b, c) __builtin_amdgcn_mfma_f32_16x16x32_bf16(a, b, c, 0, 0, 0)
#define MFMA16(PH, F0, F1, F2, F3)                                                                    \
  __builtin_amdgcn_s_setprio(1);                                                                      \
  acc[2*(PH)  ][0] = MM(F0, bk0n0, acc[2*(PH)  ][0]); acc[2*(PH)  ][1] = MM(F0, bk0n1, acc[2*(PH)  ][1]); \
  acc[2*(PH)  ][2] = MM(F0, bk0n2, acc[2*(PH)  ][2]); acc[2*(PH)  ][3] = MM(F0, bk0n3, acc[2*(PH)  ][3]); \
  acc[2*(PH)+1][0] = MM(F2, bk0n0, acc[2*(PH)+1][0]); acc[2*(PH)+1][1] = MM(F2, bk0n1, acc[2*(PH)+1][1]); \
  acc[2*(PH)+1][2] = MM(F2, bk0n2, acc[2*(PH)+1][2]); acc[2*(PH)+1][3] = MM(F2, bk0n3, acc[2*(PH)+1][3]); \
  acc[2*(PH)  ][0] = MM(F1, bk1n0, acc[2*(PH)  ][0]); acc[2*(PH)  ][1] = MM(F1, bk1n1, acc[2*(PH)  ][1]); \
  acc[2*(PH)  ][2] = MM(F1, bk1n2, acc[2*(PH)  ][2]); acc[2*(PH)  ][3] = MM(F1, bk1n3, acc[2*(PH)  ][3]); \
  acc[2*(PH)+1][0] = MM(F3, bk1n0, acc[2*(PH)+1][0]); acc[2*(PH)+1][1] = MM(F3, bk1n1, acc[2*(PH)+1][1]); \
  acc[2*(PH)+1][2] = MM(F3, bk1n2, acc[2*(PH)+1][2]); acc[2*(PH)+1][3] = MM(F3, bk1n3, acc[2*(PH)+1][3]); \
  __builtin_amdgcn_s_setprio(0);

  for (int tp = 0; tp < nk; tp += 2) {
#pragma unroll
    for (int u = 0; u < 2; ++u) {
      const int t = tp + u;
      const uint32_t bA = (uint32_t)u * 32768u;           // parity of t (and t+2)
      const uint32_t parC = (uint32_t)u;
      const uint32_t parN = (uint32_t)(1 - u);            // parity of t+1
      // ---- t-start reads: B (8) + A q0 (4) + A q1 prefetch (4)
      bf16x8 bk0n0 = *(const bf16x8*)(pB0 + bA + 0*2048);
      bf16x8 bk1n0 = *(const bf16x8*)(pB1 + bA + 0*2048);
      bf16x8 bk0n1 = *(const bf16x8*)(pB0 + bA + 1*2048);
      bf16x8 bk1n1 = *(const bf16x8*)(pB1 + bA + 1*2048);
      bf16x8 bk0n2 = *(const bf16x8*)(pB0 + bA + 2*2048);
      bf16x8 bk1n2 = *(const bf16x8*)(pB1 + bA + 2*2048);
      bf16x8 bk0n3 = *(const bf16x8*)(pB0 + bA + 3*2048);
      bf16x8 bk1n3 = *(const bf16x8*)(pB1 + bA + 3*2048);
      bf16x8 a0 = *(const bf16x8*)(pA0 + bA + 0*2048);
      bf16x8 a1 = *(const bf16x8*)(pA1 + bA + 0*2048);
      bf16x8 a2 = *(const bf16x8*)(pA0 + bA + 1*2048);
      bf16x8 a3 = *(const bf16x8*)(pA1 + bA + 1*2048);
      bf16x8 n0 = *(const bf16x8*)(pA0 + bA + 2*2048);
      bf16x8 n1 = *(const bf16x8*)(pA1 + bA + 2*2048);
      bf16x8 n2 = *(const bf16x8*)(pA0 + bA + 3*2048);
      bf16x8 n3 = *(const bf16x8*)(pA1 + bA + 3*2048);
      if (t + 1 < nk) { stA(gAr1, 8192, u + 1, parN); stA(gAr3, 24576, u + 1, parN); }
      MFMA16(0, a0, a1, a2, a3);
      asm volatile("s_barrier" ::: "memory");             // B reads drained by all
      // ---- q1-window: prefetch A q2; stage B(t+2)
      a0 = *(const bf16x8*)(pA0 + bA + 4*2048);
      a1 = *(const bf16x8*)(pA1 + bA + 4*2048);
      a2 = *(const bf16x8*)(pA0 + bA + 5*2048);
      a3 = *(const bf16x8*)(pA1 + bA + 5*2048);
      if (t + 2 < nk) { stB(gBr0, 0, u + 2, parC); stB(gBr1, 8192, u + 2, parC);
                        stB(gBr2, 16384, u + 2, parC); stB(gBr3, 24576, u + 2, parC); }
      MFMA16(1, n0, n1, n2, n3);
      asm volatile("s_barrier" ::: "memory");             // A-halfX reads drained by all
      // ---- q2-window: prefetch A q3; stage A-halfX(t+2)
      n0 = *(const bf16x8*)(pA0 + bA + 6*2048);
      n1 = *(const bf16x8*)(pA1 + bA + 6*2048);
      n2 = *(const bf16x8*)(pA0 + bA + 7*2048);
      n3 = *(const bf16x8*)(pA1 + bA + 7*2048);
      if (t + 2 < nk) { stA(gAr0, 0, u + 2, parC); stA(gAr2, 16384, u + 2, parC); }
      MFMA16(2, a0, a1, a2, a3);
      MFMA16(3, n0, n1, n2, n3);
      // ---- boundary
      if (t + 1 < nk) {
        if (t + 2 < nk) asm volatile("s_waitcnt vmcnt(6)" ::: "memory");
        else            asm volatile("s_waitcnt vmcnt(0)" ::: "memory");
        asm volatile("s_barrier" ::: "memory");
      }
    }
    gAr0 += 128; gAr1 += 128; gAr2 += 128; gAr3 += 128;
    gBr0 += 128; gBr1 += 128; gBr2 += 128; gBr3 += 128;
  }
  asm volatile("s_waitcnt vmcnt(0)" ::: "memory");        // tail: already drained
  asm volatile("s_barrier" ::: "memory");                 // GEMM LDS dead -> reuse
#undef MFMA16
#undef MM

  // epilogue: per-wave 128x64 output in two 64-row passes via LDS repack
  unsigned short* st = (unsigned short*)smem + wave * (64 * EP_STRIDE);
  const int rq4 = (lane >> 4) * 4, cq = lane & 15;
#pragma unroll
  for (int half = 0; half < 2; ++half) {
#pragma unroll
    for (int i = 0; i < 4; ++i)
#pragma unroll
      for (int j = 0; j < 4; ++j)
#pragma unroll
        for (int p = 0; p < 4; ++p)
          st[(i * 16 + rq4 + p) * EP_STRIDE + j * 16 + cq] = f2bf(acc[half * 4 + i][j][p]);
#pragma unroll
    for (int pass = 0; pass < 8; ++pass) {
      const int row = pass * 8 + (lane >> 3);
      const unsigned short* rp_ = st + row * EP_STRIDE + (lane & 7) * 8;
      u16x4 lo = *(const u16x4*)(rp_);
      u16x4 hi = *(const u16x4*)(rp_ + 4);
      u16x8 v = { lo[0], lo[1], lo[2], lo[3], hi[0], hi[1], hi[2], hi[3] };
      size_t off = (size_t)(tileM + wmRow + half * 64 + row) * N_CAT + tileN + wnRow + (lane & 7) * 8;
      *(u16x8*)(C + off) = v;
    }
  }
}

// ---------------- fused gather + mean + self + bias + ReLU + LayerNorm ----------------
// one wave per node, 4 channels/lane; single flattened edge loop, 4 edges in flight.
template <int FINAL>
__global__ __launch_bounds__(256)
void k_gather_ln(const unsigned short* __restrict__ Y, const int2* __restrict__ scN,
                 const int2* __restrict__ e2, const float* __restrict__ bias,
                 const float* __restrict__ g, const float* __restrict__ bln,
                 void* __restrict__ out) {
  const int wave = threadIdx.x >> 6, lane = threadIdx.x & 63;
  const int t = blockIdx.x * 4 + wave;
  if (t >= N_NODES) return;
  const int c0 = lane * 4;

  float a0, a1, a2, a3;
  {
    u16x4 sv = *(const u16x4*)(Y + (size_t)t * N_CAT + c0);
    f32x4 bb = *(const f32x4*)(bias + c0);
    a0 = bf2f(sv[0]) + bb[0];
    a1 = bf2f(sv[1]) + bb[1];
    a2 = bf2f(sv[2]) + bb[2];
    a3 = bf2f(sv[3]) + bb[3];
  }

  const int2 s = scN[t];                    // {start, padded_cnt (x4)}
  const int2* ep = e2 + s.x;
  for (int idx = 0; idx < s.y; idx += 4) {
    const int2 p0 = ep[idx + 0];
    const int2 p1 = ep[idx + 1];
    const int2 p2 = ep[idx + 2];
    const int2 p3 = ep[idx + 3];
    // addr: Y + src*2304 + (rel+1)*256 + c0 ; pad slots are {0,w=0} -> add 0
    const unsigned short* y0 = Y + (size_t)(p0.x & 0xFFFF) * N_CAT + (((p0.x >> 16) + 1) << 8) + c0;
    const unsigned short* y1 = Y + (size_t)(p1.x & 0xFFFF) * N_CAT + (((p1.x >> 16) + 1) << 8) + c0;
    const unsigned short* y2 = Y + (size_t)(p2.x & 0xFFFF) * N_CAT + (((p2.x >> 16) + 1) << 8) + c0;
    const unsigned short* y3 = Y + (size_t)(p3.x & 0xFFFF) * N_CAT + (((p3.x >> 16) + 1) << 8) + c0;
    u16x4 v0 = *(const u16x4*)y0;
    u16x4 v1 = *(const u16x4*)y1;
    u16x4 v2 = *(const u16x4*)y2;
    u16x4 v3 = *(const u16x4*)y3;
    const float w0 = __int_as_float(p0.y), w1 = __int_as_float(p1.y);
    const float w2 = __int_as_float(p2.y), w3 = __int_as_float(p3.y);
    a0 += w0 * bf2f(v0[0]) + w1 * bf2f(v1[0]) + w2 * bf2f(v2[0]) + w3 * bf2f(v3[0]);
    a1 += w0 * bf2f(v0[1]) + w1 * bf2f(v1[1]) + w2 * bf2f(v2[1]) + w3 * bf2f(v3[1]);
    a2 += w0 * bf2f(v0[2]) + w1 * bf2f(v1[2]) + w2 * bf2f(v2[2]) + w3 * bf2f(v3[2]);
    a3 += w0 * bf2f(v0[3]) + w1 * bf2f(v1[3]) + w2 * bf2f(v2[3]) + w3 * bf2f(v3[3]);
  }

  a0 = fmaxf(a0, 0.f); a1 = fmaxf(a1, 0.f); a2 = fmaxf(a2, 0.f); a3 = fmaxf(a3, 0.f);

  float s1 = (a0 + a1) + (a2 + a3);
#pragma unroll
  for (int off = 32; off > 0; off >>= 1) s1 += __shfl_xor(s1, off, 64);
  const float mu = s1 * (1.f / 256.f);
  const float d0 = a0 - mu, d1 = a1 - mu, d2 = a2 - mu, d3 = a3 - mu;
  float s2 = (d0 * d0 + d1 * d1) + (d2 * d2 + d3 * d3);
#pragma unroll
  for (int off = 32; off > 0; off >>= 1) s2 += __shfl_xor(s2, off, 64);
  const float rs = rsqrtf(s2 * (1.f / 256.f) + LN_EPS);

  f32x4 gg = *(const f32x4*)(g + c0);
  f32x4 ll = *(const f32x4*)(bln + c0);
  const float o0 = d0 * rs * gg[0] + ll[0];
  const float o1 = d1 * rs * gg[1] + ll[1];
  const float o2 = d2 * rs * gg[2] + ll[2];
  const float o3 = d3 * rs * gg[3] + ll[3];
  if (FINAL) {
    f32x4 o = { o0, o1, o2, o3 };
    *(f32x4*)((float*)out + (size_t)t * 256 + c0) = o;
  } else {
    u16x4 o = { f2bf(o0), f2bf(o1), f2bf(o2), f2bf(o3) };
    *(u16x4*)((unsigned short*)out + (size_t)t * 256 + c0) = o;
  }
}

// ---------------- launch ----------------
extern "C" void kernel_launch(void* const* d_in, const int* in_sizes, int n_in,
                              void* d_out, int out_size, void* d_ws, size_t ws_size,
                              hipStream_t stream) {
  (void)in_sizes; (void)n_in; (void)out_size; (void)ws_size;
  const float* x   = (const float*)d_in[0];
  const float* nw  = (const float*)d_in[1];
  const int*   esrc = (const int*)d_in[2];
  const int*   etgt = (const int*)d_in[3];
  const float* Wr0 = (const float*)d_in[4];
  const float* Ws0 = (const float*)d_in[5];
  const float* Wb0 = (const float*)d_in[6];
  const float* g0  = (const float*)d_in[7];
  const float* b0  = (const float*)d_in[8];
  const float* Wr1 = (const float*)d_in[9];
  const float* Ws1 = (const float*)d_in[10];
  const float* Wb1 = (const float*)d_in[11];
  const float* g1  = (const float*)d_in[12];
  const float* b1  = (const float*)d_in[13];

  char* p = (char*)d_ws;
  auto carve = [&](size_t bytes) {
    char* q = p;
    p += (bytes + 511) & ~(size_t)511;
    return q;
  };
  unsigned short* Y   = (unsigned short*)carve((size_t)M_PAD * N_CAT * 2);  // 231.2 MB
  unsigned short* xb  = (unsigned short*)carve((size_t)M_PAD * D_IN * 2);   //  77.1 MB
  unsigned short* h   = (unsigned short*)carve((size_t)M_PAD * D_H * 2);    //  25.7 MB
  unsigned short* Wt0 = (unsigned short*)carve((size_t)N_CAT * D_IN * 2);
  unsigned short* Wt1 = (unsigned short*)carve((size_t)N_CAT * D_H * 2);
  int*   deg     = (int*)carve((size_t)R_REL * N_NODES * 4);
  int*   pdeg    = (int*)carve((size_t)N_NODES * 4);
  int*   cursor  = (int*)carve((size_t)N_NODES * 4);
  int*   nodeptr = (int*)carve((size_t)(N_NODES + 1) * 4);
  int*   bsum    = (int*)carve((size_t)NCHUNK * 4);
  int*   chunkoff= (int*)carve((size_t)NCHUNK * 4);
  int2*  e2      = (int2*)carve((size_t)E_PAD_MAX * 8);
  int2*  scN     = (int2*)carve((size_t)N_NODES * 8);

  // CSR build (node-major; shared by both layers)
  hipMemsetAsync(deg, 0, (size_t)R_REL * N_NODES * 4, stream);
  hipMemsetAsync(cursor, 0, (size_t)N_NODES * 4, stream);
  hipMemsetAsync(e2, 0, (size_t)E_PAD_MAX * 8, stream);   // pad slots -> {src0, w=0}
  k_deg<<<(R_REL * E_EDGES + 255) / 256, 256, 0, stream>>>(etgt, deg);
  k_ndeg<<<(N_NODES + 255) / 256, 256, 0, stream>>>(deg, pdeg);
  k_scan1<<<NCHUNK, 256, 0, stream>>>(pdeg, nodeptr, bsum);
  k_scan2<<<1, 64, 0, stream>>>(bsum, chunkoff, nodeptr);
  k_scan3<<<NCHUNK, 256, 0, stream>>>(chunkoff, nodeptr);
  k_prep<<<(N_NODES + 255) / 256, 256, 0, stream>>>(nodeptr, scN);
  k_fill<<<(R_REL * E_EDGES + 255) / 256, 256, 0, stream>>>(esrc, etgt, nw, nodeptr,
                                                            deg, cursor, e2);
  // conversions
  k_cvt_x<<<(N_NODES * D_IN / 4 + 255) / 256, 256, 0, stream>>>(x, xb);
  k_cvt_w<<<(N_CAT * D_IN + 255) / 256, 256, 0, stream>>>(Ws0, Wr0, Wt0, D_IN);
  k_cvt_w<<<(N_CAT * D_H + 255) / 256, 256, 0, stream>>>(Ws1, Wr1, Wt1, D_H);

  // layer 0
  k_gemm<<<T_TOT256, 512, 0, stream>>>(xb, Wt0, Y, D_IN);
  k_gather_ln<0><<<N_NODES / 4, 256, 0, stream>>>(Y, scN, e2, Wb0, g0, b0, h);
  // layer 1
  k_gemm<<<T_TOT256, 512, 0, stream>>>(h, Wt1, Y, D_H);
  k_gather_ln<1><<<N_NODES / 4, 256, 0, stream>>>(Y, scN, e2, Wb1, g1, b1, d_out);
}